// Round 1
// baseline (632.075 us; speedup 1.0000x reference)
//
#include <hip/hip_runtime.h>
#include <math.h>

#define BB 8
#define SS 96
#define DD 768
#define RR 24
#define RSEQ 8
#define TAG 3
#define D3 2304   // 3*D
#define NC 72     // R*TAG

// ---------------------------------------------------------------------------
// Kernel 1: refine.  Algebraic collapse of the 24 sequential attention steps:
//   scores_k = scale*(S0 + G @ P_k),  P_{k+1} = P_k + softmax_rows(scores_k)
//   enc' = enc + P_final^T @ A
// grid: B blocks, 256 threads.
// ---------------------------------------------------------------------------
__global__ __launch_bounds__(256) void k_refine(const float* __restrict__ enc,
                                                const float* __restrict__ rel,
                                                float* __restrict__ encR) {
  const int b = blockIdx.x;
  const int t = threadIdx.x;
  __shared__ float As[RSEQ][DD + 4];   // +4 pad: breaks 768-stride bank aliasing
  __shared__ float S0[RSEQ][SS];
  __shared__ float G[RSEQ][RSEQ];
  __shared__ float P[RSEQ][SS];
  __shared__ float sc[RSEQ][SS];
  const float scale = 0.036084391824351613f;  // 1/sqrt(768)

  // stage A (8x768) into LDS, coalesced scalar
  const float* Ag = rel + (size_t)b * RSEQ * DD;
  for (int e = t; e < RSEQ * DD; e += 256) As[e / DD][e % DD] = Ag[e];
  // init P accumulator
  for (int e = t; e < RSEQ * SS; e += 256) ((float*)P)[e] = 0.f;
  __syncthreads();

  // G = A @ A^T  (8x8), threads 0..63
  if (t < 64) {
    const int r0 = t >> 3, r1 = t & 7;
    float a0 = 0.f, a1 = 0.f, a2 = 0.f, a3 = 0.f;
    for (int d = 0; d < DD; d += 4) {
      a0 += As[r0][d + 0] * As[r1][d + 0];
      a1 += As[r0][d + 1] * As[r1][d + 1];
      a2 += As[r0][d + 2] * As[r1][d + 2];
      a3 += As[r0][d + 3] * As[r1][d + 3];
    }
    G[r0][r1] = a0 + a1 + a2 + a3;
  }
  // S0 = A @ enc_b^T (8x96). lanes grouped 8-per-s so global reads broadcast.
  const float* Eb = enc + (size_t)b * SS * DD;
  for (int e = t; e < RSEQ * SS; e += 256) {
    const int r = e & 7, s = e >> 3;
    const float* row = Eb + (size_t)s * DD;
    float a0 = 0.f, a1 = 0.f, a2 = 0.f, a3 = 0.f;
    for (int d = 0; d < DD; d += 4) {
      const float4 rv = *(const float4*)&row[d];
      a0 += As[r][d + 0] * rv.x;
      a1 += As[r][d + 1] * rv.y;
      a2 += As[r][d + 2] * rv.z;
      a3 += As[r][d + 3] * rv.w;
    }
    S0[r][s] = a0 + a1 + a2 + a3;
  }
  __syncthreads();

  const int wave = t >> 6, lane = t & 63;
  for (int step = 0; step < RR; ++step) {
    // scores = scale*(S0 + G@P)
    for (int e = t; e < RSEQ * SS; e += 256) {
      const int r = e / SS, s = e % SS;
      float acc = S0[r][s];
#pragma unroll
      for (int r2 = 0; r2 < RSEQ; ++r2) acc += G[r][r2] * P[r2][s];
      sc[r][s] = acc * scale;
    }
    __syncthreads();
    // row softmax (over 96), wave w owns rows 2w, 2w+1; accumulate into P
#pragma unroll
    for (int rr = 0; rr < 2; ++rr) {
      const int r = wave * 2 + rr;
      const float m1 = sc[r][lane];
      const float m2 = (lane < 32) ? sc[r][lane + 64] : -1e30f;
      float mx = fmaxf(m1, m2);
#pragma unroll
      for (int o = 32; o > 0; o >>= 1) mx = fmaxf(mx, __shfl_xor(mx, o, 64));
      const float e1 = __expf(m1 - mx);
      const float e2 = (lane < 32) ? __expf(m2 - mx) : 0.f;
      float sm = e1 + e2;
#pragma unroll
      for (int o = 32; o > 0; o >>= 1) sm += __shfl_xor(sm, o, 64);
      const float inv = 1.f / sm;
      P[r][lane] += e1 * inv;
      if (lane < 32) P[r][lane + 64] += e2 * inv;
    }
    __syncthreads();
  }

  // enc' = enc + P^T @ A   (96x768), float4 along d
  float* Ob = encR + (size_t)b * SS * DD;
  for (int e = t; e < SS * DD / 4; e += 256) {
    const int s = (e * 4) / DD;
    const int d = (e * 4) % DD;
    float4 v = ((const float4*)Eb)[e];
#pragma unroll
    for (int r = 0; r < RSEQ; ++r) {
      const float p = P[r][s];
      v.x += p * As[r][d + 0];
      v.y += p * As[r][d + 1];
      v.z += p * As[r][d + 2];
      v.w += p * As[r][d + 3];
    }
    ((float4*)Ob)[e] = v;
  }
}

// ---------------------------------------------------------------------------
// Kernel 2: projection GEMM. C[768, 4608] = enc'[768,768] @ [Wh | Wt].
// n < 2304 -> Hh (+= proj_b folded), else Ht.  BM=BN=64, BK=16, 4x4/thread.
// grid: (12, 72), block 256.
// ---------------------------------------------------------------------------
__global__ __launch_bounds__(256) void k_proj(const float* __restrict__ X,
                                              const float* __restrict__ Wfull,
                                              const float* __restrict__ pb,
                                              float* __restrict__ Hh,
                                              float* __restrict__ Ht) {
  const int m0 = blockIdx.x * 64;
  const int nt = blockIdx.y;  // 0..71 ; 0..35 = Hh cols, 36..71 = Ht cols
  const bool isH = nt < 36;
  const int n0 = (isH ? nt : nt - 36) * 64;
  const float* W = Wfull + (isH ? 0 : (size_t)DD * D3);
  float* Cout = isH ? Hh : Ht;

  __shared__ float Xs[16][64];
  __shared__ float Ws[16][64];
  const int t = threadIdx.x;
  const int tx = t & 15, ty = t >> 4;

  float acc[4][4];
#pragma unroll
  for (int a = 0; a < 4; ++a)
#pragma unroll
    for (int q = 0; q < 4; ++q) acc[a][q] = 0.f;

  const int lm = t >> 2;        // X stage: m-rel 0..63
  const int lk = (t & 3) * 4;   // X stage: k-rel {0,4,8,12}
  const int wk = t >> 4;        // W stage: k-rel 0..15
  const int wn = (t & 15) * 4;  // W stage: n-rel

  for (int k0 = 0; k0 < DD; k0 += 16) {
    const float4 xv = *(const float4*)&X[(size_t)(m0 + lm) * DD + k0 + lk];
    const float4 wv = *(const float4*)&W[(size_t)(k0 + wk) * D3 + n0 + wn];
    __syncthreads();
    Xs[lk + 0][lm] = xv.x;
    Xs[lk + 1][lm] = xv.y;
    Xs[lk + 2][lm] = xv.z;
    Xs[lk + 3][lm] = xv.w;
    *(float4*)&Ws[wk][wn] = wv;
    __syncthreads();
#pragma unroll
    for (int k = 0; k < 16; ++k) {
      const float4 xa = *(const float4*)&Xs[k][ty * 4];
      const float4 wb = *(const float4*)&Ws[k][tx * 4];
      acc[0][0] += xa.x * wb.x; acc[0][1] += xa.x * wb.y; acc[0][2] += xa.x * wb.z; acc[0][3] += xa.x * wb.w;
      acc[1][0] += xa.y * wb.x; acc[1][1] += xa.y * wb.y; acc[1][2] += xa.y * wb.z; acc[1][3] += xa.y * wb.w;
      acc[2][0] += xa.z * wb.x; acc[2][1] += xa.z * wb.y; acc[2][2] += xa.z * wb.z; acc[2][3] += xa.z * wb.w;
      acc[3][0] += xa.w * wb.x; acc[3][1] += xa.w * wb.y; acc[3][2] += xa.w * wb.z; acc[3][3] += xa.w * wb.w;
    }
  }

  float4 bias = make_float4(0.f, 0.f, 0.f, 0.f);
  if (isH) bias = *(const float4*)&pb[n0 + tx * 4];
#pragma unroll
  for (int a = 0; a < 4; ++a) {
    float4 o = make_float4(acc[a][0] + bias.x, acc[a][1] + bias.y,
                           acc[a][2] + bias.z, acc[a][3] + bias.w);
    *(float4*)&Cout[(size_t)(m0 + ty * 4 + a) * D3 + n0 + tx * 4] = o;
  }
}

// ---------------------------------------------------------------------------
// Kernel 3: the big pairwise GEMM.
// out[b,tg,r,i,j] = rel_b[c] + sum_k relu(Hh'[b,i,k] + Ht[b,j,k]) * rel_W[k,c]
// One workgroup per (b,i): M'=96 (all j), N=72, K=2304 in BK=32 chunks.
// Thread tile 3j x 9c = 27 acc. grid: 768 blocks, block 256.
// ---------------------------------------------------------------------------
__global__ __launch_bounds__(256) void k_pairs(const float* __restrict__ Hh,
                                               const float* __restrict__ Ht,
                                               const float* __restrict__ relW,
                                               const float* __restrict__ relb,
                                               float* __restrict__ out) {
  const int bi = blockIdx.x;
  const int b = bi / SS, i = bi % SS;
  const int t = threadIdx.x;
  __shared__ float Hrow[D3];        // 9.2 KB
  __shared__ float Pt[SS][33];      // 12.7 KB (pad: j-stride 33 -> conflict-free)
  __shared__ float Wt[32][NC + 1];  // 9.3 KB (pad: k-stride 73)

  // stage Hh'[b,i,:]
  const float* hh = Hh + (size_t)bi * D3;
  for (int e = t; e < D3 / 4; e += 256) ((float4*)Hrow)[e] = ((const float4*)hh)[e];

  const int cg = t & 7;    // c0 = cg*9  (9*cg mod 32 all distinct -> no conflict)
  const int jg = t >> 3;   // j0 = jg*3  (3*jg mod 32 all distinct -> no conflict)
  const int c0 = cg * 9, j0 = jg * 3;
  float a0[9], a1[9], a2[9];
#pragma unroll
  for (int c = 0; c < 9; ++c) { a0[c] = 0.f; a1[c] = 0.f; a2[c] = 0.f; }

  const float* htb = Ht + (size_t)b * SS * D3;

  for (int k0 = 0; k0 < D3; k0 += 32) {
    __syncthreads();  // prev chunk's reads done (also fences Hrow on iter 0)
    // stage P = relu(Hrow + Ht[j]) : 96 x 32
#pragma unroll
    for (int pass = 0; pass < 3; ++pass) {
      const int j = (t >> 3) + pass * 32;
      const int kq = (t & 7) * 4;
      const float4 hv = *(const float4*)&htb[(size_t)j * D3 + k0 + kq];
      const float4 hr = *(const float4*)&Hrow[k0 + kq];
      Pt[j][kq + 0] = fmaxf(hr.x + hv.x, 0.f);
      Pt[j][kq + 1] = fmaxf(hr.y + hv.y, 0.f);
      Pt[j][kq + 2] = fmaxf(hr.z + hv.z, 0.f);
      Pt[j][kq + 3] = fmaxf(hr.w + hv.w, 0.f);
    }
    // stage rel_W tile 32 x 72 (contiguous global -> coalesced)
#pragma unroll
    for (int p = 0; p < 9; ++p) {
      const int e = t + p * 256;
      Wt[e / NC][e % NC] = relW[(size_t)k0 * NC + e];
    }
    __syncthreads();
#pragma unroll 2
    for (int k = 0; k < 32; ++k) {
      const float p0 = Pt[j0][k];
      const float p1 = Pt[j0 + 1][k];
      const float p2 = Pt[j0 + 2][k];
      const float* wr = &Wt[k][c0];
#pragma unroll
      for (int c = 0; c < 9; ++c) {
        const float w = wr[c];
        a0[c] += p0 * w;
        a1[c] += p1 * w;
        a2[c] += p2 * w;
      }
    }
  }

  // epilogue: c = r*3 + tg ; out[b, tg, r, i, j]
#pragma unroll
  for (int c = 0; c < 9; ++c) {
    const int cc = c0 + c;
    const int r = cc / 3, tg = cc % 3;
    const float bias = relb[cc];
    float* op = out + ((((size_t)b * TAG + tg) * RR + r) * SS + i) * SS + j0;
    op[0] = a0[c] + bias;
    op[1] = a1[c] + bias;
    op[2] = a2[c] + bias;
  }
}

// ---------------------------------------------------------------------------
extern "C" void kernel_launch(void* const* d_in, const int* in_sizes, int n_in,
                              void* d_out, int out_size, void* d_ws, size_t ws_size,
                              hipStream_t stream) {
  const float* enc   = (const float*)d_in[0];  // [8,96,768]
  const float* rel   = (const float*)d_in[1];  // [24,8,768]
  const float* projW = (const float*)d_in[2];  // [1536,2304]
  const float* projb = (const float*)d_in[3];  // [2304]
  const float* relW  = (const float*)d_in[4];  // [2304,72]
  const float* relb  = (const float*)d_in[5];  // [72]
  float* out = (float*)d_out;                  // [8,3,24,96,96]

  float* encR = (float*)d_ws;                         // 589824 floats
  float* Hh = encR + (size_t)BB * SS * DD;            // 1769472 floats (bias folded)
  float* Ht = Hh + (size_t)BB * SS * D3;              // 1769472 floats

  k_refine<<<BB, 256, 0, stream>>>(enc, rel, encR);
  k_proj<<<dim3(12, 72), 256, 0, stream>>>(encR, projW, projb, Hh, Ht);
  k_pairs<<<BB * SS, 256, 0, stream>>>(Hh, Ht, relW, relb, out);
}

// Round 2
// 352.103 us; speedup vs baseline: 1.7951x; 1.7951x over previous
//
#include <hip/hip_runtime.h>
#include <hip/hip_bf16.h>
#include <math.h>
#include <stdint.h>
#include <string.h>

#define BB 8
#define SS 96
#define DD 768
#define RR 24
#define RSEQ 8
#define TAG 3
#define D3 2304   // 3*D
#define NC 72     // R*TAG

typedef __attribute__((ext_vector_type(8))) short bf16x8;
typedef __attribute__((ext_vector_type(4))) float f32x4;

// RNE float->bf16 pair pack (compiler may lower to v_cvt_pk_bf16_f32)
static __device__ inline uint32_t pk_bf16(float lo, float hi) {
  __hip_bfloat162 h2 = __float22bfloat162_rn(make_float2(lo, hi));
  uint32_t u;
  memcpy(&u, &h2, 4);
  return u;
}

// ---------------------------------------------------------------------------
// Kernel 0: prep. Wb[96][2304] bf16 = rel_W^T (n-major, k contiguous; rows
// 72..95 zero). One-time ~0.4 MB; layout matches MFMA B-fragment reads
// (lane reads 8 consecutive k for fixed n).
// ---------------------------------------------------------------------------
__global__ __launch_bounds__(256) void k_prep(const float* __restrict__ relW,
                                              uint16_t* __restrict__ Wb) {
  const int e = blockIdx.x * 256 + threadIdx.x;  // 96*2304 = 221184 total
  const int n = e / D3, k = e % D3;
  float v = (n < NC) ? relW[(size_t)k * NC + n] : 0.f;
  uint32_t u;
  memcpy(&u, &v, 4);
  u += 0x7FFF + ((u >> 16) & 1);
  Wb[e] = (uint16_t)(u >> 16);
}

// ---------------------------------------------------------------------------
// Kernel 1: refine (unchanged from round 1 — algebraic collapse of the 24
// sequential attention steps).
// ---------------------------------------------------------------------------
__global__ __launch_bounds__(256) void k_refine(const float* __restrict__ enc,
                                                const float* __restrict__ rel,
                                                float* __restrict__ encR) {
  const int b = blockIdx.x;
  const int t = threadIdx.x;
  __shared__ float As[RSEQ][DD + 4];
  __shared__ float S0[RSEQ][SS];
  __shared__ float G[RSEQ][RSEQ];
  __shared__ float P[RSEQ][SS];
  __shared__ float sc[RSEQ][SS];
  const float scale = 0.036084391824351613f;  // 1/sqrt(768)

  const float* Ag = rel + (size_t)b * RSEQ * DD;
  for (int e = t; e < RSEQ * DD; e += 256) As[e / DD][e % DD] = Ag[e];
  for (int e = t; e < RSEQ * SS; e += 256) ((float*)P)[e] = 0.f;
  __syncthreads();

  if (t < 64) {
    const int r0 = t >> 3, r1 = t & 7;
    float a0 = 0.f, a1 = 0.f, a2 = 0.f, a3 = 0.f;
    for (int d = 0; d < DD; d += 4) {
      a0 += As[r0][d + 0] * As[r1][d + 0];
      a1 += As[r0][d + 1] * As[r1][d + 1];
      a2 += As[r0][d + 2] * As[r1][d + 2];
      a3 += As[r0][d + 3] * As[r1][d + 3];
    }
    G[r0][r1] = a0 + a1 + a2 + a3;
  }
  const float* Eb = enc + (size_t)b * SS * DD;
  for (int e = t; e < RSEQ * SS; e += 256) {
    const int r = e & 7, s = e >> 3;
    const float* row = Eb + (size_t)s * DD;
    float a0 = 0.f, a1 = 0.f, a2 = 0.f, a3 = 0.f;
    for (int d = 0; d < DD; d += 4) {
      const float4 rv = *(const float4*)&row[d];
      a0 += As[r][d + 0] * rv.x;
      a1 += As[r][d + 1] * rv.y;
      a2 += As[r][d + 2] * rv.z;
      a3 += As[r][d + 3] * rv.w;
    }
    S0[r][s] = a0 + a1 + a2 + a3;
  }
  __syncthreads();

  const int wave = t >> 6, lane = t & 63;
  for (int step = 0; step < RR; ++step) {
    for (int e = t; e < RSEQ * SS; e += 256) {
      const int r = e / SS, s = e % SS;
      float acc = S0[r][s];
#pragma unroll
      for (int r2 = 0; r2 < RSEQ; ++r2) acc += G[r][r2] * P[r2][s];
      sc[r][s] = acc * scale;
    }
    __syncthreads();
#pragma unroll
    for (int rr = 0; rr < 2; ++rr) {
      const int r = wave * 2 + rr;
      const float m1 = sc[r][lane];
      const float m2 = (lane < 32) ? sc[r][lane + 64] : -1e30f;
      float mx = fmaxf(m1, m2);
#pragma unroll
      for (int o = 32; o > 0; o >>= 1) mx = fmaxf(mx, __shfl_xor(mx, o, 64));
      const float e1 = __expf(m1 - mx);
      const float e2 = (lane < 32) ? __expf(m2 - mx) : 0.f;
      float sm = e1 + e2;
#pragma unroll
      for (int o = 32; o > 0; o >>= 1) sm += __shfl_xor(sm, o, 64);
      const float inv = 1.f / sm;
      P[r][lane] += e1 * inv;
      if (lane < 32) P[r][lane + 64] += e2 * inv;
    }
    __syncthreads();
  }

  float* Ob = encR + (size_t)b * SS * DD;
  for (int e = t; e < SS * DD / 4; e += 256) {
    const int s = (e * 4) / DD;
    const int d = (e * 4) % DD;
    float4 v = ((const float4*)Eb)[e];
#pragma unroll
    for (int r = 0; r < RSEQ; ++r) {
      const float p = P[r][s];
      v.x += p * As[r][d + 0];
      v.y += p * As[r][d + 1];
      v.z += p * As[r][d + 2];
      v.w += p * As[r][d + 3];
    }
    ((float4*)Ob)[e] = v;
  }
}

// ---------------------------------------------------------------------------
// Kernel 2: projection GEMM (unchanged from round 1).
// ---------------------------------------------------------------------------
__global__ __launch_bounds__(256) void k_proj(const float* __restrict__ X,
                                              const float* __restrict__ Wfull,
                                              const float* __restrict__ pb,
                                              float* __restrict__ Hh,
                                              float* __restrict__ Ht) {
  const int m0 = blockIdx.x * 64;
  const int nt = blockIdx.y;
  const bool isH = nt < 36;
  const int n0 = (isH ? nt : nt - 36) * 64;
  const float* W = Wfull + (isH ? 0 : (size_t)DD * D3);
  float* Cout = isH ? Hh : Ht;

  __shared__ float Xs[16][64];
  __shared__ float Ws[16][64];
  const int t = threadIdx.x;
  const int tx = t & 15, ty = t >> 4;

  float acc[4][4];
#pragma unroll
  for (int a = 0; a < 4; ++a)
#pragma unroll
    for (int q = 0; q < 4; ++q) acc[a][q] = 0.f;

  const int lm = t >> 2;
  const int lk = (t & 3) * 4;
  const int wk = t >> 4;
  const int wn = (t & 15) * 4;

  for (int k0 = 0; k0 < DD; k0 += 16) {
    const float4 xv = *(const float4*)&X[(size_t)(m0 + lm) * DD + k0 + lk];
    const float4 wv = *(const float4*)&W[(size_t)(k0 + wk) * D3 + n0 + wn];
    __syncthreads();
    Xs[lk + 0][lm] = xv.x;
    Xs[lk + 1][lm] = xv.y;
    Xs[lk + 2][lm] = xv.z;
    Xs[lk + 3][lm] = xv.w;
    *(float4*)&Ws[wk][wn] = wv;
    __syncthreads();
#pragma unroll
    for (int k = 0; k < 16; ++k) {
      const float4 xa = *(const float4*)&Xs[k][ty * 4];
      const float4 wb = *(const float4*)&Ws[k][tx * 4];
      acc[0][0] += xa.x * wb.x; acc[0][1] += xa.x * wb.y; acc[0][2] += xa.x * wb.z; acc[0][3] += xa.x * wb.w;
      acc[1][0] += xa.y * wb.x; acc[1][1] += xa.y * wb.y; acc[1][2] += xa.y * wb.z; acc[1][3] += xa.y * wb.w;
      acc[2][0] += xa.z * wb.x; acc[2][1] += xa.z * wb.y; acc[2][2] += xa.z * wb.z; acc[2][3] += xa.z * wb.w;
      acc[3][0] += xa.w * wb.x; acc[3][1] += xa.w * wb.y; acc[3][2] += xa.w * wb.z; acc[3][3] += xa.w * wb.w;
    }
  }

  float4 bias = make_float4(0.f, 0.f, 0.f, 0.f);
  if (isH) bias = *(const float4*)&pb[n0 + tx * 4];
#pragma unroll
  for (int a = 0; a < 4; ++a) {
    float4 o = make_float4(acc[a][0] + bias.x, acc[a][1] + bias.y,
                           acc[a][2] + bias.z, acc[a][3] + bias.w);
    *(float4*)&Cout[(size_t)(m0 + ty * 4 + a) * D3 + n0 + tx * 4] = o;
  }
}

// ---------------------------------------------------------------------------
// Kernel 3: pairwise GEMM via bf16 MFMA 16x16x32.
// Per block (b,i): C[96 j, 72 c] = relu(Hh[i,:] + Ht[j,:]) @ rel_W + rel_b.
// 4 waves as 2x2: wm = j-half (48 rows, 3 M-tiles), wn = c-half
// (wn=0: tiles n0 0/16/32; wn=1: 48/64 — N padded to 80, 11% waste).
// A-frags built in registers from LDS (relu+cvt), B-frags straight from
// the pre-transposed bf16 Wb (L1-resident).
// ---------------------------------------------------------------------------
__global__ __launch_bounds__(256) void k_pairs(const float* __restrict__ Hh,
                                               const float* __restrict__ Ht,
                                               const uint16_t* __restrict__ Wb,
                                               const float* __restrict__ relb,
                                               float* __restrict__ out) {
  const int bi = blockIdx.x;
  const int b = bi / SS, i = bi % SS;
  const int t = threadIdx.x;
  const int wid = t >> 6, lane = t & 63;
  const int wm = wid >> 1, wn = wid & 1;
  const int lm = lane & 15, q = lane >> 4;

  __shared__ float Hrow[D3];      // 9.2 KB
  __shared__ float Hts[SS][36];   // 13.8 KB; stride 36: float4-aligned, 2-way-max banks

  const float* hh = Hh + (size_t)bi * D3;
  for (int e = t; e < D3 / 4; e += 256) ((float4*)Hrow)[e] = ((const float4*)hh)[e];

  const int ntiles = 3 - wn;  // wn=0: cols 0..47, wn=1: cols 48..79 (pad to 80)
  f32x4 acc[3][3];
#pragma unroll
  for (int a = 0; a < 3; ++a)
#pragma unroll
    for (int c = 0; c < 3; ++c) acc[a][c] = (f32x4){0.f, 0.f, 0.f, 0.f};

  const float* htb = Ht + (size_t)b * SS * D3;

  for (int k0 = 0; k0 < D3; k0 += 32) {
    __syncthreads();  // prev reads done (also fences Hrow stage on iter 0)
    // stage Ht[b][0..95][k0..k0+31] -> LDS (coalesced: 8 lanes per 128B row-seg)
#pragma unroll
    for (int p = 0; p < 3; ++p) {
      const int e = t + p * 256;
      const int j = e >> 3, kq = (e & 7) * 4;
      *(float4*)&Hts[j][kq] = *(const float4*)&htb[(size_t)j * D3 + k0 + kq];
    }
    __syncthreads();

    // A-fragments: A[m=lm][k=q*8+jj] = relu(Hrow[k] + Ht[j][k]), 8 consecutive k
    const float4 h0 = *(const float4*)&Hrow[k0 + q * 8];      // broadcast in group
    const float4 h1 = *(const float4*)&Hrow[k0 + q * 8 + 4];
    bf16x8 afr[3];
#pragma unroll
    for (int mt = 0; mt < 3; ++mt) {
      const int j = wm * 48 + mt * 16 + lm;
      const float4 a0 = *(const float4*)&Hts[j][q * 8];
      const float4 a1 = *(const float4*)&Hts[j][q * 8 + 4];
      const float p0 = fmaxf(a0.x + h0.x, 0.f);
      const float p1 = fmaxf(a0.y + h0.y, 0.f);
      const float p2 = fmaxf(a0.z + h0.z, 0.f);
      const float p3 = fmaxf(a0.w + h0.w, 0.f);
      const float p4 = fmaxf(a1.x + h1.x, 0.f);
      const float p5 = fmaxf(a1.y + h1.y, 0.f);
      const float p6 = fmaxf(a1.z + h1.z, 0.f);
      const float p7 = fmaxf(a1.w + h1.w, 0.f);
      union { bf16x8 v; uint32_t u[4]; } pk;
      pk.u[0] = pk_bf16(p0, p1);
      pk.u[1] = pk_bf16(p2, p3);
      pk.u[2] = pk_bf16(p4, p5);
      pk.u[3] = pk_bf16(p6, p7);
      afr[mt] = pk.v;
    }

    // B-fragments from global (bf16, k-contiguous) + MFMAs
#pragma unroll
    for (int nt = 0; nt < 3; ++nt) {
      if (nt < ntiles) {
        const int n = wn * 48 + nt * 16 + lm;
        const bf16x8 bfr = *(const bf16x8*)&Wb[(size_t)n * D3 + k0 + q * 8];
#pragma unroll
        for (int mt = 0; mt < 3; ++mt)
          acc[mt][nt] = __builtin_amdgcn_mfma_f32_16x16x32_bf16(afr[mt], bfr, acc[mt][nt], 0, 0, 0);
      }
    }
  }

  // epilogue: C layout col=lm (c), row=q*4+reg (j). Lane stores float4 of 4 j.
#pragma unroll
  for (int nt = 0; nt < 3; ++nt) {
    if (nt < ntiles) {
      const int c = wn * 48 + nt * 16 + lm;
      if (c < NC) {
        const float rb = relb[c];
        const int r = c / 3, tg = c % 3;
        float* base = out + ((((size_t)b * TAG + tg) * RR + r) * SS + i) * SS;
#pragma unroll
        for (int mt = 0; mt < 3; ++mt) {
          const int j0 = wm * 48 + mt * 16 + q * 4;
          float4 o;
          o.x = acc[mt][nt].x + rb;
          o.y = acc[mt][nt].y + rb;
          o.z = acc[mt][nt].z + rb;
          o.w = acc[mt][nt].w + rb;
          *(float4*)&base[j0] = o;
        }
      }
    }
  }
}

// ---------------------------------------------------------------------------
extern "C" void kernel_launch(void* const* d_in, const int* in_sizes, int n_in,
                              void* d_out, int out_size, void* d_ws, size_t ws_size,
                              hipStream_t stream) {
  const float* enc   = (const float*)d_in[0];  // [8,96,768]
  const float* rel   = (const float*)d_in[1];  // [24,8,768]
  const float* projW = (const float*)d_in[2];  // [1536,2304]
  const float* projb = (const float*)d_in[3];  // [2304]
  const float* relW  = (const float*)d_in[4];  // [2304,72]
  const float* relb  = (const float*)d_in[5];  // [72]
  float* out = (float*)d_out;                  // [8,3,24,96,96]

  float* encR = (float*)d_ws;                         // 589824 floats
  float* Hh = encR + (size_t)BB * SS * DD;            // 1769472 floats (bias folded)
  float* Ht = Hh + (size_t)BB * SS * D3;              // 1769472 floats
  uint16_t* Wb = (uint16_t*)(Ht + (size_t)BB * SS * D3);  // 96*2304 bf16

  k_prep<<<(96 * D3) / 256, 256, 0, stream>>>(relW, Wb);
  k_refine<<<BB, 256, 0, stream>>>(enc, rel, encR);
  k_proj<<<dim3(12, 72), 256, 0, stream>>>(encR, projW, projb, Hh, Ht);
  k_pairs<<<BB * SS, 256, 0, stream>>>(Hh, Ht, Wb, relb, out);
}

// Round 3
// 346.860 us; speedup vs baseline: 1.8223x; 1.0151x over previous
//
#include <hip/hip_runtime.h>
#include <hip/hip_bf16.h>
#include <math.h>
#include <stdint.h>
#include <string.h>

#define BB 8
#define SS 96
#define DD 768
#define RR 24
#define RSEQ 8
#define TAG 3
#define D3 2304   // 3*D
#define NC 72     // R*TAG

typedef __attribute__((ext_vector_type(8))) short bf16x8;
typedef __attribute__((ext_vector_type(4))) float f32x4;

// round-half-up f32 pair -> packed bf16x2 (4 VALU: add,add,shr,and_or)
static __device__ inline uint32_t pkrhu(float lo, float hi) {
  uint32_t a, b;
  memcpy(&a, &lo, 4);
  memcpy(&b, &hi, 4);
  return ((a + 0x8000u) >> 16) | ((b + 0x8000u) & 0xFFFF0000u);
}
// RNE f32 -> bf16 (cold paths)
static __device__ inline uint32_t pkrne(float lo, float hi) {
  uint32_t a, b;
  memcpy(&a, &lo, 4);
  memcpy(&b, &hi, 4);
  a += 0x7FFFu + ((a >> 16) & 1u);
  b += 0x7FFFu + ((b >> 16) & 1u);
  return (a >> 16) | (b & 0xFFFF0000u);
}

// ---------------------------------------------------------------------------
// Kernel P0: Wb[96][2304] bf16 = rel_W^T (rows 72..95 zero). B-frag layout:
// k contiguous per n-row.
// ---------------------------------------------------------------------------
__global__ __launch_bounds__(256) void k_prepW(const float* __restrict__ relW,
                                               uint16_t* __restrict__ Wb) {
  const int e = blockIdx.x * 256 + threadIdx.x;  // 96*2304
  const int n = e / D3, k = e % D3;
  float v = (n < NC) ? relW[(size_t)k * NC + n] : 0.f;
  uint32_t u;
  memcpy(&u, &v, 4);
  u += 0x7FFFu + ((u >> 16) & 1u);
  Wb[e] = (uint16_t)(u >> 16);
}

// ---------------------------------------------------------------------------
// Kernel P1: T[2304][1536] bf16 = proj_W^T, 64x64 LDS-tiled transpose.
// grid (2304/64=36, 1536/64=24).
// ---------------------------------------------------------------------------
__global__ __launch_bounds__(256) void k_trans(const float* __restrict__ W,
                                               uint16_t* __restrict__ T) {
  __shared__ float tile[64][65];
  const int c0 = blockIdx.x * 64;  // input col = output row
  const int r0 = blockIdx.y * 64;  // input row = output col
  const int t = threadIdx.x;
  {
    const int tr = t >> 4;
    const int tc4 = (t & 15) * 4;
#pragma unroll
    for (int p = 0; p < 4; ++p) {
      const int r = tr + p * 16;
      const float4 v = *(const float4*)&W[(size_t)(r0 + r) * D3 + c0 + tc4];
      tile[r][tc4 + 0] = v.x;
      tile[r][tc4 + 1] = v.y;
      tile[r][tc4 + 2] = v.z;
      tile[r][tc4 + 3] = v.w;
    }
  }
  __syncthreads();
  {
    const int cc = t >> 4;
    const int rr4 = (t & 15) * 4;
#pragma unroll
    for (int p = 0; p < 4; ++p) {
      const int c = cc + p * 16;
      uint2 w;
      w.x = pkrne(tile[rr4 + 0][c], tile[rr4 + 1][c]);
      w.y = pkrne(tile[rr4 + 2][c], tile[rr4 + 3][c]);
      *(uint2*)&T[(size_t)(c0 + c) * (2 * DD) + r0 + rr4] = w;
    }
  }
}

// ---------------------------------------------------------------------------
// Kernel 1: refine (algebraic collapse of 24 sequential attention steps).
// Output: enc' as bf16 [768 rows (b*96+s)][768], k-contiguous (MFMA A layout).
// ---------------------------------------------------------------------------
__global__ __launch_bounds__(256) void k_refine(const float* __restrict__ enc,
                                                const float* __restrict__ rel,
                                                uint16_t* __restrict__ encRb) {
  const int b = blockIdx.x;
  const int t = threadIdx.x;
  __shared__ float As[RSEQ][DD + 4];
  __shared__ float S0[RSEQ][SS];
  __shared__ float G[RSEQ][RSEQ];
  __shared__ float P[RSEQ][SS];
  __shared__ float sc[RSEQ][SS];
  const float scale = 0.036084391824351613f;  // 1/sqrt(768)

  const float* Ag = rel + (size_t)b * RSEQ * DD;
  for (int e = t; e < RSEQ * DD; e += 256) As[e / DD][e % DD] = Ag[e];
  for (int e = t; e < RSEQ * SS; e += 256) ((float*)P)[e] = 0.f;
  __syncthreads();

  if (t < 64) {
    const int r0 = t >> 3, r1 = t & 7;
    float a0 = 0.f, a1 = 0.f, a2 = 0.f, a3 = 0.f;
    for (int d = 0; d < DD; d += 4) {
      a0 += As[r0][d + 0] * As[r1][d + 0];
      a1 += As[r0][d + 1] * As[r1][d + 1];
      a2 += As[r0][d + 2] * As[r1][d + 2];
      a3 += As[r0][d + 3] * As[r1][d + 3];
    }
    G[r0][r1] = a0 + a1 + a2 + a3;
  }
  const float* Eb = enc + (size_t)b * SS * DD;
  for (int e = t; e < RSEQ * SS; e += 256) {
    const int r = e & 7, s = e >> 3;
    const float* row = Eb + (size_t)s * DD;
    float a0 = 0.f, a1 = 0.f, a2 = 0.f, a3 = 0.f;
    for (int d = 0; d < DD; d += 4) {
      const float4 rv = *(const float4*)&row[d];
      a0 += As[r][d + 0] * rv.x;
      a1 += As[r][d + 1] * rv.y;
      a2 += As[r][d + 2] * rv.z;
      a3 += As[r][d + 3] * rv.w;
    }
    S0[r][s] = a0 + a1 + a2 + a3;
  }
  __syncthreads();

  const int wave = t >> 6, lane = t & 63;
  for (int step = 0; step < RR; ++step) {
    for (int e = t; e < RSEQ * SS; e += 256) {
      const int r = e / SS, s = e % SS;
      float acc = S0[r][s];
#pragma unroll
      for (int r2 = 0; r2 < RSEQ; ++r2) acc += G[r][r2] * P[r2][s];
      sc[r][s] = acc * scale;
    }
    __syncthreads();
#pragma unroll
    for (int rr = 0; rr < 2; ++rr) {
      const int r = wave * 2 + rr;
      const float m1 = sc[r][lane];
      const float m2 = (lane < 32) ? sc[r][lane + 64] : -1e30f;
      float mx = fmaxf(m1, m2);
#pragma unroll
      for (int o = 32; o > 0; o >>= 1) mx = fmaxf(mx, __shfl_xor(mx, o, 64));
      const float e1 = __expf(m1 - mx);
      const float e2 = (lane < 32) ? __expf(m2 - mx) : 0.f;
      float sm = e1 + e2;
#pragma unroll
      for (int o = 32; o > 0; o >>= 1) sm += __shfl_xor(sm, o, 64);
      const float inv = 1.f / sm;
      P[r][lane] += e1 * inv;
      if (lane < 32) P[r][lane + 64] += e2 * inv;
    }
    __syncthreads();
  }

  uint16_t* Ob = encRb + (size_t)b * SS * DD;
  for (int e = t; e < SS * DD / 4; e += 256) {
    const int s = (e * 4) / DD;
    const int d = (e * 4) % DD;
    float4 v = ((const float4*)Eb)[e];
#pragma unroll
    for (int r = 0; r < RSEQ; ++r) {
      const float p = P[r][s];
      v.x += p * As[r][d + 0];
      v.y += p * As[r][d + 1];
      v.z += p * As[r][d + 2];
      v.w += p * As[r][d + 3];
    }
    uint2 w;
    w.x = pkrhu(v.x, v.y);
    w.y = pkrhu(v.z, v.w);
    *(uint2*)&Ob[e * 4] = w;
  }
}

// ---------------------------------------------------------------------------
// Kernel 2: projection GEMM via bf16 MFMA, no LDS (A/B frags from global,
// L2-served). C[768, 4608] = enc'b @ [Wh|Wt]^T-frags. Block tile 128m x 64n,
// 4 waves 2x2, per wave 4 mt x 2 nt. grid (6, 72).
// ---------------------------------------------------------------------------
__global__ __launch_bounds__(256) void k_proj(const uint16_t* __restrict__ Ab,
                                              const uint16_t* __restrict__ Bt,
                                              const float* __restrict__ pb,
                                              float* __restrict__ Hh,
                                              float* __restrict__ Ht) {
  const int m0 = blockIdx.x * 128;
  const int gn0 = blockIdx.y * 64;
  const bool isH = gn0 < D3;              // uniform per block
  const int n0loc = isH ? gn0 : gn0 - D3; // output column base (0..2303)
  const int halfk = isH ? 0 : DD;         // Wh vs Wt half of proj_W^T
  float* Cout = isH ? Hh : Ht;

  const int t = threadIdx.x, wid = t >> 6, lane = t & 63;
  const int wm = wid >> 1, wn = wid & 1, lm = lane & 15, q = lane >> 4;
  const int kq = q * 8;

  size_t aoff[4];
#pragma unroll
  for (int mt = 0; mt < 4; ++mt)
    aoff[mt] = (size_t)(m0 + wm * 64 + mt * 16 + lm) * DD;
  size_t boff[2];
#pragma unroll
  for (int nt = 0; nt < 2; ++nt)
    boff[nt] = (size_t)(n0loc + wn * 32 + nt * 16 + lm) * (2 * DD) + halfk;

  f32x4 acc[4][2];
#pragma unroll
  for (int a = 0; a < 4; ++a)
#pragma unroll
    for (int c = 0; c < 2; ++c) acc[a][c] = (f32x4){0.f, 0.f, 0.f, 0.f};

  bf16x8 ac[4], bc[2];
#pragma unroll
  for (int mt = 0; mt < 4; ++mt) ac[mt] = *(const bf16x8*)&Ab[aoff[mt] + kq];
#pragma unroll
  for (int nt = 0; nt < 2; ++nt) bc[nt] = *(const bf16x8*)&Bt[boff[nt] + kq];

  for (int k0 = 0; k0 < DD - 32; k0 += 32) {
    bf16x8 an[4], bn[2];
    const int kn = k0 + 32 + kq;
#pragma unroll
    for (int mt = 0; mt < 4; ++mt) an[mt] = *(const bf16x8*)&Ab[aoff[mt] + kn];
#pragma unroll
    for (int nt = 0; nt < 2; ++nt) bn[nt] = *(const bf16x8*)&Bt[boff[nt] + kn];
#pragma unroll
    for (int nt = 0; nt < 2; ++nt)
#pragma unroll
      for (int mt = 0; mt < 4; ++mt)
        acc[mt][nt] = __builtin_amdgcn_mfma_f32_16x16x32_bf16(ac[mt], bc[nt], acc[mt][nt], 0, 0, 0);
#pragma unroll
    for (int mt = 0; mt < 4; ++mt) ac[mt] = an[mt];
#pragma unroll
    for (int nt = 0; nt < 2; ++nt) bc[nt] = bn[nt];
  }
#pragma unroll
  for (int nt = 0; nt < 2; ++nt)
#pragma unroll
    for (int mt = 0; mt < 4; ++mt)
      acc[mt][nt] = __builtin_amdgcn_mfma_f32_16x16x32_bf16(ac[mt], bc[nt], acc[mt][nt], 0, 0, 0);

  // epilogue: C layout col=lm, row=q*4+reg
#pragma unroll
  for (int nt = 0; nt < 2; ++nt) {
    const int ncol = n0loc + wn * 32 + nt * 16 + lm;
    const float bias = isH ? pb[ncol] : 0.f;
#pragma unroll
    for (int mt = 0; mt < 4; ++mt) {
      const int m = m0 + wm * 64 + mt * 16 + q * 4;
#pragma unroll
      for (int r = 0; r < 4; ++r)
        Cout[(size_t)(m + r) * D3 + ncol] = acc[mt][nt][r] + bias;
    }
  }
}

// ---------------------------------------------------------------------------
// Kernel 3: pairwise GEMM via bf16 MFMA 16x16x32, cooperative P-build.
// Per block (b,i): C[96 j, 72 c] = relu(Hh[i,:] + Ht[j,:]) @ rel_W + rel_b.
// K-chunk 64: all 256 threads build P (bf16, once) into LDS Pb[96][72]
// (stride 72 bf16 = 144B: b128 reads 2-way-free; build map j=t&31,o=t>>5
// gives conflict-free writes). Waves 2x2 (wm: j-half, wn: c-half).
// ---------------------------------------------------------------------------
__global__ __launch_bounds__(256) void k_pairs(const float* __restrict__ Hh,
                                               const float* __restrict__ Ht,
                                               const uint16_t* __restrict__ Wb,
                                               const float* __restrict__ relb,
                                               float* __restrict__ out) {
  const int bi = blockIdx.x;
  const int b = bi / SS, i = bi % SS;
  const int t = threadIdx.x;
  const int wid = t >> 6, lane = t & 63;
  const int wm = wid >> 1, wn = wid & 1;
  const int lm = lane & 15, q = lane >> 4;

  __shared__ float Hrow[D3];          // 9.2 KB
  __shared__ uint16_t Pb[SS][NC];     // 13.5 KB (only cols 0..63 used as data)

  const float* hh = Hh + (size_t)bi * D3;
  for (int e = t; e < D3 / 4; e += 256) ((float4*)Hrow)[e] = ((const float4*)hh)[e];
  __syncthreads();

  const int ntiles = 3 - wn;  // wn=0: c-tiles 0/16/32; wn=1: 48/64 (N pad 80)
  f32x4 acc[3][3];
#pragma unroll
  for (int a = 0; a < 3; ++a)
#pragma unroll
    for (int c = 0; c < 3; ++c) acc[a][c] = (f32x4){0.f, 0.f, 0.f, 0.f};

  const float* htb = Ht + (size_t)b * SS * D3;
  const int jb = t & 31;   // build: j base
  const int ko = t >> 5;   // build: k-octet 0..7 within chunk

  for (int k0 = 0; k0 < D3; k0 += 64) {
    // ---- build phase: P = relu(Hrow + Ht[j]) -> bf16 LDS, built ONCE ----
    const float4 h0 = *(const float4*)&Hrow[k0 + ko * 8];
    const float4 h1 = *(const float4*)&Hrow[k0 + ko * 8 + 4];
#pragma unroll
    for (int p = 0; p < 3; ++p) {
      const int j = jb + p * 32;
      const float4 v0 = *(const float4*)&htb[(size_t)j * D3 + k0 + ko * 8];
      const float4 v1 = *(const float4*)&htb[(size_t)j * D3 + k0 + ko * 8 + 4];
      uint4 w;
      w.x = pkrhu(fmaxf(v0.x + h0.x, 0.f), fmaxf(v0.y + h0.y, 0.f));
      w.y = pkrhu(fmaxf(v0.z + h0.z, 0.f), fmaxf(v0.w + h0.w, 0.f));
      w.z = pkrhu(fmaxf(v1.x + h1.x, 0.f), fmaxf(v1.y + h1.y, 0.f));
      w.w = pkrhu(fmaxf(v1.z + h1.z, 0.f), fmaxf(v1.w + h1.w, 0.f));
      *(uint4*)&Pb[j][ko * 8] = w;
    }
    __syncthreads();

    // ---- MFMA phase: A-frags from LDS (ds_read_b128), B from global ----
#pragma unroll
    for (int kw = 0; kw < 2; ++kw) {
      bf16x8 afr[3];
#pragma unroll
      for (int mt = 0; mt < 3; ++mt)
        afr[mt] = *(const bf16x8*)&Pb[wm * 48 + mt * 16 + lm][kw * 32 + q * 8];
#pragma unroll
      for (int nt = 0; nt < 3; ++nt) {
        if (nt < ntiles) {
          const int n = wn * 48 + nt * 16 + lm;
          const bf16x8 bfr = *(const bf16x8*)&Wb[(size_t)n * D3 + k0 + kw * 32 + q * 8];
#pragma unroll
          for (int mt = 0; mt < 3; ++mt)
            acc[mt][nt] = __builtin_amdgcn_mfma_f32_16x16x32_bf16(afr[mt], bfr, acc[mt][nt], 0, 0, 0);
        }
      }
    }
    __syncthreads();  // Pb reads done before next build overwrites
  }

  // epilogue: C layout col=lm (c), row=q*4+reg (j)
#pragma unroll
  for (int nt = 0; nt < 3; ++nt) {
    if (nt < ntiles) {
      const int c = wn * 48 + nt * 16 + lm;
      if (c < NC) {
        const float rb = relb[c];
        const int r = c / 3, tg = c % 3;
        float* base = out + ((((size_t)b * TAG + tg) * RR + r) * SS + i) * SS;
#pragma unroll
        for (int mt = 0; mt < 3; ++mt) {
          const int j0 = wm * 48 + mt * 16 + q * 4;
          float4 o;
          o.x = acc[mt][nt][0] + rb;
          o.y = acc[mt][nt][1] + rb;
          o.z = acc[mt][nt][2] + rb;
          o.w = acc[mt][nt][3] + rb;
          *(float4*)&base[j0] = o;
        }
      }
    }
  }
}

// ---------------------------------------------------------------------------
extern "C" void kernel_launch(void* const* d_in, const int* in_sizes, int n_in,
                              void* d_out, int out_size, void* d_ws, size_t ws_size,
                              hipStream_t stream) {
  const float* enc   = (const float*)d_in[0];  // [8,96,768]
  const float* rel   = (const float*)d_in[1];  // [24,8,768]
  const float* projW = (const float*)d_in[2];  // [1536,2304]
  const float* projb = (const float*)d_in[3];  // [2304]
  const float* relW  = (const float*)d_in[4];  // [2304,72]
  const float* relb  = (const float*)d_in[5];  // [72]
  float* out = (float*)d_out;                  // [8,3,24,96,96]

  float* Hh = (float*)d_ws;                               // 768*2304 f32
  float* Ht = Hh + (size_t)DD * D3;                       // 768*2304 f32
  uint16_t* Wb = (uint16_t*)(Ht + (size_t)DD * D3);       // 96*2304 bf16
  uint16_t* Tp = Wb + (size_t)96 * D3;                    // 2304*1536 bf16 (projW^T)
  uint16_t* Ab = Tp + (size_t)D3 * 2 * DD;                // 768*768 bf16 (enc')

  k_prepW<<<(96 * D3) / 256, 256, 0, stream>>>(relW, Wb);
  k_trans<<<dim3(36, 24), 256, 0, stream>>>(projW, Tp);
  k_refine<<<BB, 256, 0, stream>>>(enc, rel, Ab);
  k_proj<<<dim3(6, 72), 256, 0, stream>>>(Ab, Tp, projb, Hh, Ht);
  k_pairs<<<BB * SS, 256, 0, stream>>>(Hh, Ht, Wb, relb, out);
}